// Round 1
// baseline (4221.718 us; speedup 1.0000x reference)
//
#include <hip/hip_runtime.h>
#include <math.h>

// Problem constants (from reference)
#define N_G   60000
#define N_D   40000
#define NTOT  100000          // N_G + N_D
#define DIM   64
#define E_EDGES 1600000
#define B_BATCH 4096
#define K_NEG   1
#define DECAY_F 1e-4f

// ---------------------------------------------------------------------------
// Kernel 1: agg = concat(gene_embed, drug_embed); mean = exp(-t) * agg (hop 0)
// One thread per float4 (N*16 threads).
// ---------------------------------------------------------------------------
__global__ void init_agg_mean(const float* __restrict__ ge, const float* __restrict__ de,
                              const float* __restrict__ gt, const float* __restrict__ dt,
                              float* __restrict__ agg, float* __restrict__ mean) {
    int idx = blockIdx.x * blockDim.x + threadIdx.x;   // float4 index
    const int total = NTOT * (DIM / 4);
    if (idx >= total) return;
    int node = idx / (DIM / 4);
    int sub  = idx % (DIM / 4);
    float4 v;
    float t;
    if (node < N_G) {
        v = ((const float4*)ge)[node * (DIM / 4) + sub];
        t = gt[node];
    } else {
        int dn = node - N_G;
        v = ((const float4*)de)[dn * (DIM / 4) + sub];
        t = dt[dn];
    }
    ((float4*)agg)[idx] = v;
    float w = expf(-t);                    // hk(t, 0) = exp(-t)
    float4 m = make_float4(v.x * w, v.y * w, v.z * w, v.w * w);
    ((float4*)mean)[idx] = m;
}

// ---------------------------------------------------------------------------
// Kernel 2: push-style SpMM with atomics.
// 16 threads per edge; each thread handles 4 consecutive floats (float4 read,
// 4 scalar atomicAdds). side[row] += val * agg[col].
// ---------------------------------------------------------------------------
__global__ void spmm_atomic(const float* __restrict__ aval, const int* __restrict__ arow,
                            const int* __restrict__ acol, const float* __restrict__ agg,
                            float* __restrict__ side) {
    int idx = blockIdx.x * blockDim.x + threadIdx.x;
    const int total = E_EDGES * 16;
    if (idx >= total) return;
    int e   = idx >> 4;
    int sub = idx & 15;
    float v = aval[e];
    int c = acol[e];
    int r = arow[e];
    float4 a = ((const float4*)agg)[c * (DIM / 4) + sub];
    float* dst = side + (size_t)r * DIM + sub * 4;
    atomicAdd(dst + 0, v * a.x);
    atomicAdd(dst + 1, v * a.y);
    atomicAdd(dst + 2, v * a.z);
    atomicAdd(dst + 3, v * a.w);
}

// ---------------------------------------------------------------------------
// Kernel 3: mean += hk(t, k) * side    (hk(t,k) = exp(-t) t^k / k!)
// ---------------------------------------------------------------------------
__global__ void scale_accum(const float* __restrict__ gt, const float* __restrict__ dt,
                            const float* __restrict__ side, float* __restrict__ mean,
                            int k, float inv_fact) {
    int idx = blockIdx.x * blockDim.x + threadIdx.x;   // float4 index
    const int total = NTOT * (DIM / 4);
    if (idx >= total) return;
    int node = idx / (DIM / 4);
    float t = (node < N_G) ? gt[node] : dt[node - N_G];
    float tp = t;
    for (int i = 1; i < k; ++i) tp *= t;
    float w = expf(-t) * tp * inv_fact;
    float4 s = ((const float4*)side)[idx];
    float4 m = ((float4*)mean)[idx];
    m.x += w * s.x; m.y += w * s.y; m.z += w * s.z; m.w += w * s.w;
    ((float4*)mean)[idx] = m;
}

// ---------------------------------------------------------------------------
// Kernel 4: loss. One 64-lane wave per batch element.
// g_e = mean[user]/4, pos_e = mean[N_G+pos]/4, neg_e = mean[N_G+neg]/4
// pos/neg scores via wave reduce; reg terms recomputed from raw embeddings.
// ---------------------------------------------------------------------------
__global__ void loss_kernel(const float* __restrict__ mean,
                            const float* __restrict__ ge, const float* __restrict__ de,
                            const float* __restrict__ gt, const float* __restrict__ dt,
                            const int* __restrict__ user, const int* __restrict__ pos,
                            const int* __restrict__ neg, float* __restrict__ accum) {
    int gtid = blockIdx.x * blockDim.x + threadIdx.x;
    int wave = gtid >> 6;
    int lane = gtid & 63;
    if (wave >= B_BATCH) return;

    int u = user[wave];
    int p = pos[wave];

    float g  = mean[(size_t)u * DIM + lane] * 0.25f;
    float pe = mean[(size_t)(N_G + p) * DIM + lane] * 0.25f;
    float dotp = g * pe;

    // K = 1 negative
    int n0 = neg[wave * K_NEG + 0];
    float ne = mean[(size_t)(N_G + n0) * DIM + lane] * 0.25f;
    float dotn = g * ne;

    // hop-0 regularization terms (embs[0] recomputed from raw embeddings)
    float g0 = expf(-gt[u])  * ge[(size_t)u  * DIM + lane];
    float p0 = expf(-dt[p])  * de[(size_t)p  * DIM + lane];
    float q0 = expf(-dt[n0]) * de[(size_t)n0 * DIM + lane];
    float reg = g0 * g0 + p0 * p0 + q0 * q0;

    // wave64 reduction
    #pragma unroll
    for (int off = 32; off > 0; off >>= 1) {
        dotp += __shfl_down(dotp, off);
        dotn += __shfl_down(dotn, off);
        reg  += __shfl_down(reg,  off);
    }
    if (lane == 0) {
        float x = dotn - dotp;
        // log1p(exp(x)) stable
        float mf = fmaxf(x, 0.0f) + log1pf(expf(-fabsf(x)));
        atomicAdd(&accum[0], mf);
        atomicAdd(&accum[1], reg);
    }
}

// ---------------------------------------------------------------------------
// Kernel 5: finalize -> 3 scalars
// ---------------------------------------------------------------------------
__global__ void finalize(const float* __restrict__ accum, float* __restrict__ out) {
    float mf  = accum[0] / (float)B_BATCH;
    float emb = DECAY_F * (accum[1] * 0.5f) / (float)B_BATCH;
    out[0] = mf + emb;
    out[1] = mf;
    out[2] = emb;
}

extern "C" void kernel_launch(void* const* d_in, const int* in_sizes, int n_in,
                              void* d_out, int out_size, void* d_ws, size_t ws_size,
                              hipStream_t stream) {
    const float* ge   = (const float*)d_in[0];   // gene_embed (N_G, 64)
    const float* de   = (const float*)d_in[1];   // drug_embed (N_D, 64)
    const float* gt   = (const float*)d_in[2];   // gene_t (N_G, 1)
    const float* dt   = (const float*)d_in[3];   // drug_t (N_D, 1)
    const float* aval = (const float*)d_in[4];   // adj_val (E,)
    const int*   arow = (const int*)d_in[5];     // adj_row (E,)
    const int*   acol = (const int*)d_in[6];     // adj_col (E,)
    const int*   user = (const int*)d_in[7];     // (B,)
    const int*   pos  = (const int*)d_in[8];     // (B,)
    const int*   neg  = (const int*)d_in[9];     // (B, K)
    float* out = (float*)d_out;

    // Workspace layout: bufA | bufB | mean | accum(2 floats). Needs ~76.8 MB.
    char* ws = (char*)d_ws;
    const size_t bufBytes = (size_t)NTOT * DIM * sizeof(float);
    float* bufA  = (float*)(ws);
    float* bufB  = (float*)(ws + bufBytes);
    float* meanb = (float*)(ws + 2 * bufBytes);
    float* accum = (float*)(ws + 3 * bufBytes);

    hipMemsetAsync(accum, 0, 2 * sizeof(float), stream);

    const int tot4 = NTOT * (DIM / 4);
    init_agg_mean<<<(tot4 + 255) / 256, 256, 0, stream>>>(ge, de, gt, dt, bufA, meanb);

    const float inv_fact[4] = {1.0f, 1.0f, 0.5f, 1.0f / 6.0f};
    float* agg  = bufA;
    float* side = bufB;
    for (int k = 1; k <= 3; ++k) {
        hipMemsetAsync(side, 0, bufBytes, stream);
        spmm_atomic<<<(E_EDGES * 16 + 255) / 256, 256, 0, stream>>>(aval, arow, acol, agg, side);
        scale_accum<<<(tot4 + 255) / 256, 256, 0, stream>>>(gt, dt, side, meanb, k, inv_fact[k]);
        float* tmp = agg; agg = side; side = tmp;
    }

    loss_kernel<<<(B_BATCH * 64 + 255) / 256, 256, 0, stream>>>(meanb, ge, de, gt, dt,
                                                                user, pos, neg, accum);
    finalize<<<1, 1, 0, stream>>>(accum, out);
}

// Round 2
// 1051.925 us; speedup vs baseline: 4.0133x; 4.0133x over previous
//
#include <hip/hip_runtime.h>
#include <math.h>

// Problem constants (from reference)
#define N_G   60000
#define N_D   40000
#define NTOT  100000          // N_G + N_D
#define DIM   64
#define E_EDGES 1600000
#define B_BATCH 4096
#define K_NEG   1
#define DECAY_F 1e-4f

// ---------------------------------------------------------------------------
// Kernel 1: agg = concat(gene_embed, drug_embed); mean = exp(-t) * agg (hop 0)
// ---------------------------------------------------------------------------
__global__ void init_agg_mean(const float* __restrict__ ge, const float* __restrict__ de,
                              const float* __restrict__ gt, const float* __restrict__ dt,
                              float* __restrict__ agg, float* __restrict__ mean) {
    int idx = blockIdx.x * blockDim.x + threadIdx.x;   // float4 index
    const int total = NTOT * (DIM / 4);
    if (idx >= total) return;
    int node = idx / (DIM / 4);
    int sub  = idx % (DIM / 4);
    float4 v;
    float t;
    if (node < N_G) {
        v = ((const float4*)ge)[node * (DIM / 4) + sub];
        t = gt[node];
    } else {
        int dn = node - N_G;
        v = ((const float4*)de)[dn * (DIM / 4) + sub];
        t = dt[dn];
    }
    ((float4*)agg)[idx] = v;
    float w = expf(-t);                    // hk(t, 0) = exp(-t)
    ((float4*)mean)[idx] = make_float4(v.x * w, v.y * w, v.z * w, v.w * w);
}

// ---------------------------------------------------------------------------
// CSR build: histogram -> scan -> scatter
// ---------------------------------------------------------------------------
__global__ void k_count(const int* __restrict__ arow, int* __restrict__ cnt) {
    int e = blockIdx.x * blockDim.x + threadIdx.x;
    if (e >= E_EDGES) return;
    atomicAdd(&cnt[arow[e]], 1);
}

// Single-block exclusive scan of cnt[0..NTOT) -> row_ptr[0..NTOT], cursor copy.
__global__ void k_scan(const int* __restrict__ cnt, int* __restrict__ row_ptr,
                       int* __restrict__ cursor) {
    __shared__ int sums[1024];
    int t = threadIdx.x;
    const int CH = (NTOT + 1023) / 1024;   // 98 elems per thread
    int base = t * CH;
    int s = 0;
    for (int i = 0; i < CH; ++i) {
        int idx = base + i;
        if (idx < NTOT) s += cnt[idx];
    }
    sums[t] = s;
    __syncthreads();
    // Hillis-Steele inclusive scan (read-all, barrier, write-all)
    for (int off = 1; off < 1024; off <<= 1) {
        int v = (t >= off) ? sums[t - off] : 0;
        __syncthreads();
        sums[t] += v;
        __syncthreads();
    }
    int run = (t == 0) ? 0 : sums[t - 1];
    for (int i = 0; i < CH; ++i) {
        int idx = base + i;
        if (idx < NTOT) {
            row_ptr[idx] = run;
            cursor[idx]  = run;
            run += cnt[idx];
        }
    }
    if (t == 1023) row_ptr[NTOT] = run;    // == E_EDGES
}

__global__ void k_scatter(const int* __restrict__ arow, const int* __restrict__ acol,
                          const float* __restrict__ aval, int* __restrict__ cursor,
                          int* __restrict__ col_s, float* __restrict__ val_s) {
    int e = blockIdx.x * blockDim.x + threadIdx.x;
    if (e >= E_EDGES) return;
    int r = arow[e];
    int pos = atomicAdd(&cursor[r], 1);
    col_s[pos] = acol[e];
    val_s[pos] = aval[e];
}

// ---------------------------------------------------------------------------
// Pull-style SpMM, fused with mean accumulation.
// One wave64 per row; lane l holds element l of the row (256B coalesced per edge).
//   side[row] = sum_e val*agg[col]   (skipped when write_side==0)
//   mean[row] += hk(t,k) * side[row]
// ---------------------------------------------------------------------------
__global__ void spmm_pull(const int* __restrict__ row_ptr, const int* __restrict__ col_s,
                          const float* __restrict__ val_s, const float* __restrict__ agg,
                          float* __restrict__ side, float* __restrict__ mean,
                          const float* __restrict__ gt, const float* __restrict__ dt,
                          int k, float inv_fact, int write_side) {
    int gtid = blockIdx.x * blockDim.x + threadIdx.x;
    int row  = gtid >> 6;
    int lane = gtid & 63;
    if (row >= NTOT) return;
    int s = row_ptr[row];
    int e = row_ptr[row + 1];
    float acc = 0.0f;
    for (; s < e; ++s) {
        int   c = col_s[s];            // wave-uniform -> broadcast
        float v = val_s[s];
        acc = fmaf(v, agg[(size_t)c * DIM + lane], acc);
    }
    if (write_side) side[(size_t)row * DIM + lane] = acc;
    float t = (row < N_G) ? gt[row] : dt[row - N_G];
    float tp = t;
    for (int i = 1; i < k; ++i) tp *= t;
    float w = expf(-t) * tp * inv_fact;
    size_t mi = (size_t)row * DIM + lane;
    mean[mi] += w * acc;
}

// ---------------------------------------------------------------------------
// Loss: one wave64 per batch element.
// ---------------------------------------------------------------------------
__global__ void loss_kernel(const float* __restrict__ mean,
                            const float* __restrict__ ge, const float* __restrict__ de,
                            const float* __restrict__ gt, const float* __restrict__ dt,
                            const int* __restrict__ user, const int* __restrict__ pos,
                            const int* __restrict__ neg, float* __restrict__ accum) {
    int gtid = blockIdx.x * blockDim.x + threadIdx.x;
    int wave = gtid >> 6;
    int lane = gtid & 63;
    if (wave >= B_BATCH) return;

    int u = user[wave];
    int p = pos[wave];
    int n0 = neg[wave * K_NEG + 0];

    float g  = mean[(size_t)u * DIM + lane] * 0.25f;
    float pe = mean[(size_t)(N_G + p) * DIM + lane] * 0.25f;
    float ne = mean[(size_t)(N_G + n0) * DIM + lane] * 0.25f;
    float dotp = g * pe;
    float dotn = g * ne;

    float g0 = expf(-gt[u])  * ge[(size_t)u  * DIM + lane];
    float p0 = expf(-dt[p])  * de[(size_t)p  * DIM + lane];
    float q0 = expf(-dt[n0]) * de[(size_t)n0 * DIM + lane];
    float reg = g0 * g0 + p0 * p0 + q0 * q0;

    #pragma unroll
    for (int off = 32; off > 0; off >>= 1) {
        dotp += __shfl_down(dotp, off);
        dotn += __shfl_down(dotn, off);
        reg  += __shfl_down(reg,  off);
    }
    if (lane == 0) {
        float x = dotn - dotp;
        float mf = fmaxf(x, 0.0f) + log1pf(expf(-fabsf(x)));   // log1p(exp(x))
        atomicAdd(&accum[0], mf);
        atomicAdd(&accum[1], reg);
    }
}

__global__ void finalize(const float* __restrict__ accum, float* __restrict__ out) {
    float mf  = accum[0] / (float)B_BATCH;
    float emb = DECAY_F * (accum[1] * 0.5f) / (float)B_BATCH;
    out[0] = mf + emb;
    out[1] = mf;
    out[2] = emb;
}

extern "C" void kernel_launch(void* const* d_in, const int* in_sizes, int n_in,
                              void* d_out, int out_size, void* d_ws, size_t ws_size,
                              hipStream_t stream) {
    const float* ge   = (const float*)d_in[0];
    const float* de   = (const float*)d_in[1];
    const float* gt   = (const float*)d_in[2];
    const float* dt   = (const float*)d_in[3];
    const float* aval = (const float*)d_in[4];
    const int*   arow = (const int*)d_in[5];
    const int*   acol = (const int*)d_in[6];
    const int*   user = (const int*)d_in[7];
    const int*   pos  = (const int*)d_in[8];
    const int*   neg  = (const int*)d_in[9];
    float* out = (float*)d_out;

    // Workspace layout (bytes):
    //   bufA, bufB, mean : 3 * 25.6 MB
    //   row_ptr          : (NTOT+1) ints
    //   cursor/cnt       : NTOT ints (cnt reuses cursor before scan copies it)
    //   col_s            : E ints
    //   val_s            : E floats
    //   accum            : 2 floats
    char* ws = (char*)d_ws;
    const size_t bufBytes = (size_t)NTOT * DIM * sizeof(float);
    float* bufA    = (float*)(ws);
    float* bufB    = (float*)(ws + bufBytes);
    float* meanb   = (float*)(ws + 2 * bufBytes);
    char*  p       = ws + 3 * bufBytes;
    int*   row_ptr = (int*)p;              p += (NTOT + 1) * sizeof(int);
    int*   cnt     = (int*)p;              p += NTOT * sizeof(int);   // doubles as cursor
    int*   cursor  = (int*)p;              p += NTOT * sizeof(int);
    int*   col_s   = (int*)p;              p += (size_t)E_EDGES * sizeof(int);
    float* val_s   = (float*)p;            p += (size_t)E_EDGES * sizeof(float);
    float* accum   = (float*)p;

    hipMemsetAsync(cnt, 0, NTOT * sizeof(int), stream);
    hipMemsetAsync(accum, 0, 2 * sizeof(float), stream);

    const int tot4 = NTOT * (DIM / 4);
    init_agg_mean<<<(tot4 + 255) / 256, 256, 0, stream>>>(ge, de, gt, dt, bufA, meanb);

    // CSR build (reused by all 3 hops)
    k_count  <<<(E_EDGES + 255) / 256, 256, 0, stream>>>(arow, cnt);
    k_scan   <<<1, 1024, 0, stream>>>(cnt, row_ptr, cursor);
    k_scatter<<<(E_EDGES + 255) / 256, 256, 0, stream>>>(arow, acol, aval, cursor, col_s, val_s);

    const float inv_fact[4] = {1.0f, 1.0f, 0.5f, 1.0f / 6.0f};
    float* agg  = bufA;
    float* side = bufB;
    const int spmm_threads = NTOT * 64;
    for (int k = 1; k <= 3; ++k) {
        int write_side = (k < 3) ? 1 : 0;
        spmm_pull<<<(spmm_threads + 255) / 256, 256, 0, stream>>>(
            row_ptr, col_s, val_s, agg, side, meanb, gt, dt, k, inv_fact[k], write_side);
        float* tmp = agg; agg = side; side = tmp;
    }

    loss_kernel<<<(B_BATCH * 64 + 255) / 256, 256, 0, stream>>>(meanb, ge, de, gt, dt,
                                                                user, pos, neg, accum);
    finalize<<<1, 1, 0, stream>>>(accum, out);
}

// Round 3
// 798.091 us; speedup vs baseline: 5.2898x; 1.3181x over previous
//
#include <hip/hip_runtime.h>
#include <math.h>

// Problem constants (from reference)
#define N_G   60000
#define N_D   40000
#define NTOT  100000          // N_G + N_D
#define DIM   64
#define E_EDGES 1600000
#define B_BATCH 4096
#define K_NEG   1
#define DECAY_F 1e-4f
#define NB_SCAN ((NTOT + 1023) / 1024)   // 98 blocks for the hierarchical scan

// ---------------------------------------------------------------------------
// Kernel 1: agg = concat(gene_embed, drug_embed); mean = exp(-t) * agg (hop 0)
// ---------------------------------------------------------------------------
__global__ void init_agg_mean(const float* __restrict__ ge, const float* __restrict__ de,
                              const float* __restrict__ gt, const float* __restrict__ dt,
                              float* __restrict__ agg, float* __restrict__ mean) {
    int idx = blockIdx.x * blockDim.x + threadIdx.x;   // float4 index
    const int total = NTOT * (DIM / 4);
    if (idx >= total) return;
    int node = idx / (DIM / 4);
    int sub  = idx % (DIM / 4);
    float4 v;
    float t;
    if (node < N_G) {
        v = ((const float4*)ge)[node * (DIM / 4) + sub];
        t = gt[node];
    } else {
        int dn = node - N_G;
        v = ((const float4*)de)[dn * (DIM / 4) + sub];
        t = dt[dn];
    }
    ((float4*)agg)[idx] = v;
    float w = expf(-t);                    // hk(t, 0) = exp(-t)
    ((float4*)mean)[idx] = make_float4(v.x * w, v.y * w, v.z * w, v.w * w);
}

// ---------------------------------------------------------------------------
// CSR build: histogram -> hierarchical scan (3 kernels) -> scatter (packed int2)
// ---------------------------------------------------------------------------
__global__ void k_count(const int* __restrict__ arow, int* __restrict__ cnt) {
    int e = blockIdx.x * blockDim.x + threadIdx.x;
    if (e >= E_EDGES) return;
    atomicAdd(&cnt[arow[e]], 1);
}

// scan1: per-block (1024 elems) exclusive scan of cnt -> row_ptr; block totals.
__global__ void k_scan1(const int* __restrict__ cnt, int* __restrict__ row_ptr,
                        int* __restrict__ blocksum) {
    int gid  = blockIdx.x * 1024 + threadIdx.x;
    int lane = threadIdx.x & 63;
    int wid  = threadIdx.x >> 6;           // 16 waves
    int v = (gid < NTOT) ? cnt[gid] : 0;
    int x = v;
    #pragma unroll
    for (int off = 1; off < 64; off <<= 1) {
        int y = __shfl_up(x, off);
        if (lane >= off) x += y;
    }
    __shared__ int wsum[16];
    if (lane == 63) wsum[wid] = x;
    __syncthreads();
    if (wid == 0) {
        int w = (lane < 16) ? wsum[lane] : 0;
        #pragma unroll
        for (int off = 1; off < 16; off <<= 1) {
            int y = __shfl_up(w, off);
            if (lane >= off) w += y;
        }
        if (lane < 16) wsum[lane] = w;     // inclusive wave-sum scan
    }
    __syncthreads();
    int woff = (wid == 0) ? 0 : wsum[wid - 1];
    int incl = x + woff;
    if (gid < NTOT) row_ptr[gid] = incl - v;   // block-local exclusive
    if (threadIdx.x == 1023) blocksum[blockIdx.x] = incl;
}

// scan2: exclusive scan of the 98 block sums (single small block, 2 waves).
__global__ void k_scan2(const int* __restrict__ blocksum, int* __restrict__ blockoff) {
    int t = threadIdx.x;                   // 0..127
    int lane = t & 63;
    int wid  = t >> 6;
    int v = (t < NB_SCAN) ? blocksum[t] : 0;
    int x = v;
    #pragma unroll
    for (int off = 1; off < 64; off <<= 1) {
        int y = __shfl_up(x, off);
        if (lane >= off) x += y;
    }
    __shared__ int wsum[2];
    if (lane == 63) wsum[wid] = x;
    __syncthreads();
    int incl = x + ((wid == 1) ? wsum[0] : 0);
    if (t < NB_SCAN) blockoff[t] = incl - v;
}

// scan3: add block offsets in place; mirror into cursor; set sentinel.
__global__ void k_scan3(int* __restrict__ row_ptr, const int* __restrict__ blockoff,
                        int* __restrict__ cursor) {
    int gid = blockIdx.x * blockDim.x + threadIdx.x;
    if (gid < NTOT) {
        int r = row_ptr[gid] + blockoff[gid >> 10];
        row_ptr[gid] = r;
        cursor[gid]  = r;
    }
    if (gid == 0) row_ptr[NTOT] = E_EDGES;
}

__global__ void k_scatter(const int* __restrict__ arow, const int* __restrict__ acol,
                          const float* __restrict__ aval, int* __restrict__ cursor,
                          int2* __restrict__ edge_s) {
    int e = blockIdx.x * blockDim.x + threadIdx.x;
    if (e >= E_EDGES) return;
    int r = arow[e];
    int pos = atomicAdd(&cursor[r], 1);
    edge_s[pos] = make_int2(acol[e], __float_as_int(aval[e]));
}

// ---------------------------------------------------------------------------
// Pull-style SpMM, fused with mean accumulation.
// One wave64 per row; lane l holds element l (256B coalesced gather per edge).
// ---------------------------------------------------------------------------
__global__ void spmm_pull(const int* __restrict__ row_ptr, const int2* __restrict__ edge_s,
                          const float* __restrict__ agg,
                          float* __restrict__ side, float* __restrict__ mean,
                          const float* __restrict__ gt, const float* __restrict__ dt,
                          int k, float inv_fact, int write_side) {
    int gtid = blockIdx.x * blockDim.x + threadIdx.x;
    int row  = gtid >> 6;
    int lane = gtid & 63;
    if (row >= NTOT) return;
    int s = row_ptr[row];
    int e = row_ptr[row + 1];
    float acc = 0.0f;
    for (; s < e; ++s) {
        int2 ed = edge_s[s];               // wave-uniform 8B -> broadcast
        acc = fmaf(__int_as_float(ed.y), agg[(size_t)ed.x * DIM + lane], acc);
    }
    if (write_side) side[(size_t)row * DIM + lane] = acc;
    float t = (row < N_G) ? gt[row] : dt[row - N_G];
    float tp = t;
    for (int i = 1; i < k; ++i) tp *= t;
    float w = expf(-t) * tp * inv_fact;
    size_t mi = (size_t)row * DIM + lane;
    mean[mi] += w * acc;
}

// ---------------------------------------------------------------------------
// Loss: one wave64 per batch element.
// ---------------------------------------------------------------------------
__global__ void loss_kernel(const float* __restrict__ mean,
                            const float* __restrict__ ge, const float* __restrict__ de,
                            const float* __restrict__ gt, const float* __restrict__ dt,
                            const int* __restrict__ user, const int* __restrict__ pos,
                            const int* __restrict__ neg, float* __restrict__ accum) {
    int gtid = blockIdx.x * blockDim.x + threadIdx.x;
    int wave = gtid >> 6;
    int lane = gtid & 63;
    if (wave >= B_BATCH) return;

    int u = user[wave];
    int p = pos[wave];
    int n0 = neg[wave * K_NEG + 0];

    float g  = mean[(size_t)u * DIM + lane] * 0.25f;
    float pe = mean[(size_t)(N_G + p) * DIM + lane] * 0.25f;
    float ne = mean[(size_t)(N_G + n0) * DIM + lane] * 0.25f;
    float dotp = g * pe;
    float dotn = g * ne;

    float g0 = expf(-gt[u])  * ge[(size_t)u  * DIM + lane];
    float p0 = expf(-dt[p])  * de[(size_t)p  * DIM + lane];
    float q0 = expf(-dt[n0]) * de[(size_t)n0 * DIM + lane];
    float reg = g0 * g0 + p0 * p0 + q0 * q0;

    #pragma unroll
    for (int off = 32; off > 0; off >>= 1) {
        dotp += __shfl_down(dotp, off);
        dotn += __shfl_down(dotn, off);
        reg  += __shfl_down(reg,  off);
    }
    if (lane == 0) {
        float x = dotn - dotp;
        float mf = fmaxf(x, 0.0f) + log1pf(expf(-fabsf(x)));   // log1p(exp(x))
        atomicAdd(&accum[0], mf);
        atomicAdd(&accum[1], reg);
    }
}

__global__ void finalize(const float* __restrict__ accum, float* __restrict__ out) {
    float mf  = accum[0] / (float)B_BATCH;
    float emb = DECAY_F * (accum[1] * 0.5f) / (float)B_BATCH;
    out[0] = mf + emb;
    out[1] = mf;
    out[2] = emb;
}

extern "C" void kernel_launch(void* const* d_in, const int* in_sizes, int n_in,
                              void* d_out, int out_size, void* d_ws, size_t ws_size,
                              hipStream_t stream) {
    const float* ge   = (const float*)d_in[0];
    const float* de   = (const float*)d_in[1];
    const float* gt   = (const float*)d_in[2];
    const float* dt   = (const float*)d_in[3];
    const float* aval = (const float*)d_in[4];
    const int*   arow = (const int*)d_in[5];
    const int*   acol = (const int*)d_in[6];
    const int*   user = (const int*)d_in[7];
    const int*   pos  = (const int*)d_in[8];
    const int*   neg  = (const int*)d_in[9];
    float* out = (float*)d_out;

    // Workspace layout
    char* ws = (char*)d_ws;
    const size_t bufBytes = (size_t)NTOT * DIM * sizeof(float);
    float* bufA     = (float*)(ws);
    float* bufB     = (float*)(ws + bufBytes);
    float* meanb    = (float*)(ws + 2 * bufBytes);
    char*  p        = ws + 3 * bufBytes;
    int*   row_ptr  = (int*)p;             p += (NTOT + 1) * sizeof(int);
    int*   cnt      = (int*)p;             p += NTOT * sizeof(int);
    int*   cursor   = (int*)p;             p += NTOT * sizeof(int);
    int*   blocksum = (int*)p;             p += NB_SCAN * sizeof(int);
    int*   blockoff = (int*)p;             p += NB_SCAN * sizeof(int);
    int2*  edge_s   = (int2*)p;            p += (size_t)E_EDGES * sizeof(int2);
    float* accum    = (float*)p;

    hipMemsetAsync(cnt, 0, NTOT * sizeof(int), stream);
    hipMemsetAsync(accum, 0, 2 * sizeof(float), stream);

    const int tot4 = NTOT * (DIM / 4);
    init_agg_mean<<<(tot4 + 255) / 256, 256, 0, stream>>>(ge, de, gt, dt, bufA, meanb);

    // CSR build (reused by all 3 hops)
    k_count <<<(E_EDGES + 255) / 256, 256, 0, stream>>>(arow, cnt);
    k_scan1 <<<NB_SCAN, 1024, 0, stream>>>(cnt, row_ptr, blocksum);
    k_scan2 <<<1, 128, 0, stream>>>(blocksum, blockoff);
    k_scan3 <<<(NTOT + 255) / 256, 256, 0, stream>>>(row_ptr, blockoff, cursor);
    k_scatter<<<(E_EDGES + 255) / 256, 256, 0, stream>>>(arow, acol, aval, cursor, edge_s);

    const float inv_fact[4] = {1.0f, 1.0f, 0.5f, 1.0f / 6.0f};
    float* agg  = bufA;
    float* side = bufB;
    const int spmm_threads = NTOT * 64;
    for (int k = 1; k <= 3; ++k) {
        int write_side = (k < 3) ? 1 : 0;
        spmm_pull<<<(spmm_threads + 255) / 256, 256, 0, stream>>>(
            row_ptr, edge_s, agg, side, meanb, gt, dt, k, inv_fact[k], write_side);
        float* tmp = agg; agg = side; side = tmp;
    }

    loss_kernel<<<(B_BATCH * 64 + 255) / 256, 256, 0, stream>>>(meanb, ge, de, gt, dt,
                                                                user, pos, neg, accum);
    finalize<<<1, 1, 0, stream>>>(accum, out);
}

// Round 4
// 466.926 us; speedup vs baseline: 9.0415x; 1.7092x over previous
//
#include <hip/hip_runtime.h>
#include <math.h>

// Problem constants (from reference)
#define N_G   60000
#define N_D   40000
#define NTOT  100000          // N_G + N_D
#define DIM   64
#define E_EDGES 1600000
#define B_BATCH 4096
#define K_NEG   1
#define DECAY_F 1e-4f
#define NB_SCAN ((NTOT + 1023) / 1024)   // 98 blocks for the hierarchical scan

// ---------------------------------------------------------------------------
// CSR build: histogram -> hierarchical scan (3 kernels) -> scatter (packed int2)
// ---------------------------------------------------------------------------
__global__ void k_count(const int* __restrict__ arow, int* __restrict__ cnt) {
    int e = blockIdx.x * blockDim.x + threadIdx.x;
    if (e >= E_EDGES) return;
    atomicAdd(&cnt[arow[e]], 1);
}

// scan1: per-block (1024 elems) exclusive scan of cnt -> row_ptr; block totals.
__global__ void k_scan1(const int* __restrict__ cnt, int* __restrict__ row_ptr,
                        int* __restrict__ blocksum) {
    int gid  = blockIdx.x * 1024 + threadIdx.x;
    int lane = threadIdx.x & 63;
    int wid  = threadIdx.x >> 6;           // 16 waves
    int v = (gid < NTOT) ? cnt[gid] : 0;
    int x = v;
    #pragma unroll
    for (int off = 1; off < 64; off <<= 1) {
        int y = __shfl_up(x, off);
        if (lane >= off) x += y;
    }
    __shared__ int wsum[16];
    if (lane == 63) wsum[wid] = x;
    __syncthreads();
    if (wid == 0) {
        int w = (lane < 16) ? wsum[lane] : 0;
        #pragma unroll
        for (int off = 1; off < 16; off <<= 1) {
            int y = __shfl_up(w, off);
            if (lane >= off) w += y;
        }
        if (lane < 16) wsum[lane] = w;     // inclusive wave-sum scan
    }
    __syncthreads();
    int woff = (wid == 0) ? 0 : wsum[wid - 1];
    int incl = x + woff;
    if (gid < NTOT) row_ptr[gid] = incl - v;   // block-local exclusive
    if (threadIdx.x == 1023) blocksum[blockIdx.x] = incl;
}

// scan2: exclusive scan of the 98 block sums (single small block, 2 waves).
__global__ void k_scan2(const int* __restrict__ blocksum, int* __restrict__ blockoff) {
    int t = threadIdx.x;                   // 0..127
    int lane = t & 63;
    int wid  = t >> 6;
    int v = (t < NB_SCAN) ? blocksum[t] : 0;
    int x = v;
    #pragma unroll
    for (int off = 1; off < 64; off <<= 1) {
        int y = __shfl_up(x, off);
        if (lane >= off) x += y;
    }
    __shared__ int wsum[2];
    if (lane == 63) wsum[wid] = x;
    __syncthreads();
    int incl = x + ((wid == 1) ? wsum[0] : 0);
    if (t < NB_SCAN) blockoff[t] = incl - v;
}

// scan3: add block offsets in place; mirror into cursor; set sentinel.
__global__ void k_scan3(int* __restrict__ row_ptr, const int* __restrict__ blockoff,
                        int* __restrict__ cursor) {
    int gid = blockIdx.x * blockDim.x + threadIdx.x;
    if (gid < NTOT) {
        int r = row_ptr[gid] + blockoff[gid >> 10];
        row_ptr[gid] = r;
        cursor[gid]  = r;
    }
    if (gid == 0) row_ptr[NTOT] = E_EDGES;
}

__global__ void k_scatter(const int* __restrict__ arow, const int* __restrict__ acol,
                          const float* __restrict__ aval, int* __restrict__ cursor,
                          int2* __restrict__ edge_s) {
    int e = blockIdx.x * blockDim.x + threadIdx.x;
    if (e >= E_EDGES) return;
    int r = arow[e];
    int pos = atomicAdd(&cursor[r], 1);
    edge_s[pos] = make_int2(acol[e], __float_as_int(aval[e]));
}

// ---------------------------------------------------------------------------
// Hop 1: side1[row] = sum val * raw[col]   (raw = concat(ge, de), read in place)
// One wave64 per row; lane l holds element l. Unroll x8 for memory-level ||ism.
// ---------------------------------------------------------------------------
__global__ void spmm_first(const int* __restrict__ row_ptr, const int2* __restrict__ edge_s,
                           const float* __restrict__ ge, const float* __restrict__ de,
                           float* __restrict__ side1) {
    int gtid = blockIdx.x * blockDim.x + threadIdx.x;
    int row  = gtid >> 6;
    int lane = gtid & 63;
    if (row >= NTOT) return;
    int s = row_ptr[row];
    int e = row_ptr[row + 1];
    float acc0 = 0.0f, acc1 = 0.0f;
    for (; s + 8 <= e; s += 8) {
        int2 ed[8];
        #pragma unroll
        for (int i = 0; i < 8; ++i) ed[i] = edge_s[s + i];
        float a[8];
        #pragma unroll
        for (int i = 0; i < 8; ++i) {
            int c = ed[i].x;
            const float* base = (c < N_G) ? (ge + (size_t)c * DIM)
                                          : (de + (size_t)(c - N_G) * DIM);
            a[i] = base[lane];
        }
        #pragma unroll
        for (int i = 0; i < 8; i += 2) {
            acc0 = fmaf(__int_as_float(ed[i].y),     a[i],     acc0);
            acc1 = fmaf(__int_as_float(ed[i + 1].y), a[i + 1], acc1);
        }
    }
    for (; s < e; ++s) {
        int2 edd = edge_s[s];
        int c = edd.x;
        const float* base = (c < N_G) ? (ge + (size_t)c * DIM)
                                      : (de + (size_t)(c - N_G) * DIM);
        acc0 = fmaf(__int_as_float(edd.y), base[lane], acc0);
    }
    side1[(size_t)row * DIM + lane] = acc0 + acc1;
}

// ---------------------------------------------------------------------------
// Hop 2: side2[row] = sum val * side1[col]
// ---------------------------------------------------------------------------
__global__ void spmm_mid(const int* __restrict__ row_ptr, const int2* __restrict__ edge_s,
                         const float* __restrict__ src, float* __restrict__ dst) {
    int gtid = blockIdx.x * blockDim.x + threadIdx.x;
    int row  = gtid >> 6;
    int lane = gtid & 63;
    if (row >= NTOT) return;
    int s = row_ptr[row];
    int e = row_ptr[row + 1];
    float acc0 = 0.0f, acc1 = 0.0f;
    for (; s + 8 <= e; s += 8) {
        int2 ed[8];
        #pragma unroll
        for (int i = 0; i < 8; ++i) ed[i] = edge_s[s + i];
        float a[8];
        #pragma unroll
        for (int i = 0; i < 8; ++i) a[i] = src[(size_t)ed[i].x * DIM + lane];
        #pragma unroll
        for (int i = 0; i < 8; i += 2) {
            acc0 = fmaf(__int_as_float(ed[i].y),     a[i],     acc0);
            acc1 = fmaf(__int_as_float(ed[i + 1].y), a[i + 1], acc1);
        }
    }
    for (; s < e; ++s) {
        int2 edd = edge_s[s];
        acc0 = fmaf(__int_as_float(edd.y), src[(size_t)edd.x * DIM + lane], acc0);
    }
    dst[(size_t)row * DIM + lane] = acc0 + acc1;
}

// ---------------------------------------------------------------------------
// Hop-3 pull for a single row (used by loss): sum val * side2[col]
// ---------------------------------------------------------------------------
__device__ __forceinline__ float pull_row(const int* __restrict__ row_ptr,
                                          const int2* __restrict__ edge_s,
                                          const float* __restrict__ src,
                                          int row, int lane) {
    int s = row_ptr[row];
    int e = row_ptr[row + 1];
    float acc0 = 0.0f, acc1 = 0.0f;
    for (; s + 4 <= e; s += 4) {
        int2 e0 = edge_s[s],     e1 = edge_s[s + 1];
        int2 e2 = edge_s[s + 2], e3 = edge_s[s + 3];
        float a0 = src[(size_t)e0.x * DIM + lane];
        float a1 = src[(size_t)e1.x * DIM + lane];
        float a2 = src[(size_t)e2.x * DIM + lane];
        float a3 = src[(size_t)e3.x * DIM + lane];
        acc0 = fmaf(__int_as_float(e0.y), a0, acc0);
        acc1 = fmaf(__int_as_float(e1.y), a1, acc1);
        acc0 = fmaf(__int_as_float(e2.y), a2, acc0);
        acc1 = fmaf(__int_as_float(e3.y), a3, acc1);
    }
    for (; s < e; ++s) {
        int2 edd = edge_s[s];
        acc0 = fmaf(__int_as_float(edd.y), src[(size_t)edd.x * DIM + lane], acc0);
    }
    return acc0 + acc1;
}

// ---------------------------------------------------------------------------
// Loss: one wave64 per batch element. Computes hop-3 on the fly for its 3 rows
// and forms mean = 0.25 * (w0*raw + w1*side1 + w2*side2 + w3*side3) in regs.
// ---------------------------------------------------------------------------
__global__ void loss_kernel(const float* __restrict__ side1, const float* __restrict__ side2,
                            const int* __restrict__ row_ptr, const int2* __restrict__ edge_s,
                            const float* __restrict__ ge, const float* __restrict__ de,
                            const float* __restrict__ gt, const float* __restrict__ dt,
                            const int* __restrict__ user, const int* __restrict__ pos,
                            const int* __restrict__ neg, float* __restrict__ accum) {
    int gtid = blockIdx.x * blockDim.x + threadIdx.x;
    int wave = gtid >> 6;
    int lane = gtid & 63;
    if (wave >= B_BATCH) return;

    int u  = user[wave];
    int p  = pos[wave];
    int n0 = neg[wave * K_NEG + 0];

    // --- user (gene) row ---
    float tg  = gt[u];
    float w0g = expf(-tg);
    float w1g = w0g * tg;
    float w2g = w1g * tg * 0.5f;
    float w3g = w1g * tg * tg * (1.0f / 6.0f);
    float e0g = ge[(size_t)u * DIM + lane];
    float s1g = side1[(size_t)u * DIM + lane];
    float s2g = side2[(size_t)u * DIM + lane];
    float s3g = pull_row(row_ptr, edge_s, side2, u, lane);
    float gm  = 0.25f * (w0g * e0g + w1g * s1g + w2g * s2g + w3g * s3g);

    // --- pos (drug) row ---
    int   pr  = N_G + p;
    float tp  = dt[p];
    float w0p = expf(-tp);
    float w1p = w0p * tp;
    float w2p = w1p * tp * 0.5f;
    float w3p = w1p * tp * tp * (1.0f / 6.0f);
    float e0p = de[(size_t)p * DIM + lane];
    float s1p = side1[(size_t)pr * DIM + lane];
    float s2p = side2[(size_t)pr * DIM + lane];
    float s3p = pull_row(row_ptr, edge_s, side2, pr, lane);
    float pm  = 0.25f * (w0p * e0p + w1p * s1p + w2p * s2p + w3p * s3p);

    // --- neg (drug) row ---
    int   nr  = N_G + n0;
    float tn  = dt[n0];
    float w0n = expf(-tn);
    float w1n = w0n * tn;
    float w2n = w1n * tn * 0.5f;
    float w3n = w1n * tn * tn * (1.0f / 6.0f);
    float e0n = de[(size_t)n0 * DIM + lane];
    float s1n = side1[(size_t)nr * DIM + lane];
    float s2n = side2[(size_t)nr * DIM + lane];
    float s3n = pull_row(row_ptr, edge_s, side2, nr, lane);
    float nm  = 0.25f * (w0n * e0n + w1n * s1n + w2n * s2n + w3n * s3n);

    float dotp = gm * pm;
    float dotn = gm * nm;
    float g0 = w0g * e0g, p0 = w0p * e0p, q0 = w0n * e0n;
    float reg = g0 * g0 + p0 * p0 + q0 * q0;

    #pragma unroll
    for (int off = 32; off > 0; off >>= 1) {
        dotp += __shfl_down(dotp, off);
        dotn += __shfl_down(dotn, off);
        reg  += __shfl_down(reg,  off);
    }
    if (lane == 0) {
        float x = dotn - dotp;
        float mf = fmaxf(x, 0.0f) + log1pf(expf(-fabsf(x)));   // log1p(exp(x))
        atomicAdd(&accum[0], mf);
        atomicAdd(&accum[1], reg);
    }
}

__global__ void finalize(const float* __restrict__ accum, float* __restrict__ out) {
    float mf  = accum[0] / (float)B_BATCH;
    float emb = DECAY_F * (accum[1] * 0.5f) / (float)B_BATCH;
    out[0] = mf + emb;
    out[1] = mf;
    out[2] = emb;
}

extern "C" void kernel_launch(void* const* d_in, const int* in_sizes, int n_in,
                              void* d_out, int out_size, void* d_ws, size_t ws_size,
                              hipStream_t stream) {
    const float* ge   = (const float*)d_in[0];
    const float* de   = (const float*)d_in[1];
    const float* gt   = (const float*)d_in[2];
    const float* dt   = (const float*)d_in[3];
    const float* aval = (const float*)d_in[4];
    const int*   arow = (const int*)d_in[5];
    const int*   acol = (const int*)d_in[6];
    const int*   user = (const int*)d_in[7];
    const int*   pos  = (const int*)d_in[8];
    const int*   neg  = (const int*)d_in[9];
    float* out = (float*)d_out;

    // Workspace layout
    char* ws = (char*)d_ws;
    const size_t bufBytes = (size_t)NTOT * DIM * sizeof(float);
    float* side1    = (float*)(ws);
    float* side2    = (float*)(ws + bufBytes);
    char*  p        = ws + 2 * bufBytes;
    int*   row_ptr  = (int*)p;             p += (NTOT + 1) * sizeof(int);
    int*   cnt      = (int*)p;             p += NTOT * sizeof(int);
    int*   cursor   = (int*)p;             p += NTOT * sizeof(int);
    int*   blocksum = (int*)p;             p += NB_SCAN * sizeof(int);
    int*   blockoff = (int*)p;             p += NB_SCAN * sizeof(int);
    int2*  edge_s   = (int2*)p;            p += (size_t)E_EDGES * sizeof(int2);
    float* accum    = (float*)p;

    hipMemsetAsync(cnt, 0, NTOT * sizeof(int), stream);
    hipMemsetAsync(accum, 0, 2 * sizeof(float), stream);

    // CSR build (reused by all hops)
    k_count <<<(E_EDGES + 255) / 256, 256, 0, stream>>>(arow, cnt);
    k_scan1 <<<NB_SCAN, 1024, 0, stream>>>(cnt, row_ptr, blocksum);
    k_scan2 <<<1, 128, 0, stream>>>(blocksum, blockoff);
    k_scan3 <<<(NTOT + 255) / 256, 256, 0, stream>>>(row_ptr, blockoff, cursor);
    k_scatter<<<(E_EDGES + 255) / 256, 256, 0, stream>>>(arow, acol, aval, cursor, edge_s);

    const int spmm_blocks = (NTOT * 64 + 255) / 256;
    spmm_first<<<spmm_blocks, 256, 0, stream>>>(row_ptr, edge_s, ge, de, side1);
    spmm_mid  <<<spmm_blocks, 256, 0, stream>>>(row_ptr, edge_s, side1, side2);

    loss_kernel<<<(B_BATCH * 64 + 255) / 256, 256, 0, stream>>>(
        side1, side2, row_ptr, edge_s, ge, de, gt, dt, user, pos, neg, accum);
    finalize<<<1, 1, 0, stream>>>(accum, out);
}